// Round 1
// baseline (1845.246 us; speedup 1.0000x reference)
//
#include <hip/hip_runtime.h>
#include <math.h>

// GumbelVQTokenizer: n=131072, d=128, num_code=512
// out = [quantized (n*128) | encodings (n*512) | indices-as-float (n)]  fp32
//
// Round 0: fused fp32 baseline.
//   kernel 1: transpose codebook (512x128 -> 128x512) into d_ws
//   kernel 2: per block of 16 rows: normalize -> GEMM1(+argmax,+noise,logits in LDS)
//             -> softmax -> encodings write -> GEMM2 -> quantized write

#define N_TOK 131072
#define DIM   128
#define NC    512
#define RB    16                 // rows per block
#define NBLK  (N_TOK / RB)       // 8192
#define C1    32                 // GEMM1 code chunk
#define NCH   (NC / C1)          // 16
#define XS_S  132                // 128 + 4 pad (16B-aligned row stride)
#define CBT_S 40                 // 32 + 8 pad (16B-aligned, conflict-free col reads)
#define CBN_S 132                // 128 + 4 pad for GEMM2 tile
#define EPSF  1e-6f

__global__ __launch_bounds__(256) void transpose_cb(const float* __restrict__ cb,
                                                    float* __restrict__ cbt) {
    int idx = blockIdx.x * 256 + threadIdx.x;   // 0 .. 512*128-1
    int c = idx >> 7;         // code 0..511
    int k = idx & 127;        // dim  0..127
    cbt[k * NC + c] = cb[idx];
}

__global__ __launch_bounds__(256, 2) void vq_main(
    const float* __restrict__ x, const float* __restrict__ mask,
    const float* __restrict__ cb, const float* __restrict__ cbt_g,
    const float* __restrict__ noise,
    float* __restrict__ out_q, float* __restrict__ out_e, float* __restrict__ out_i)
{
    __shared__ __align__(16) float xs[RB][XS_S];        //  8448 B
    __shared__ __align__(16) float logits[RB][NC];      // 32768 B (later holds exp)
    __shared__ __align__(16) float cbuf[128 * CBT_S];   // 20480 B (GEMM2 aliases [32][132])
    __shared__ float red[RB][33];                       //  2112 B
    __shared__ float Mrow[RB];
    __shared__ float SInv[RB];

    const int tid  = threadIdx.x;
    const int row0 = blockIdx.x * RB;

    // ---------------- load x tile, nudge, row-normalize into LDS ----------------
    float4 v[2]; int rA[2], kq[2];
#pragma unroll
    for (int i = 0; i < 2; i++) {
        int g = tid + 256 * i;          // 0..511 float4s over 16x128
        int r = g >> 5, q = g & 31;
        rA[i] = r; kq[i] = q;
        float4 t = reinterpret_cast<const float4*>(x)[(size_t)(row0 + r) * (DIM / 4) + q];
        float nudge = (1.0f - mask[row0 + r]) * EPSF;
        t.x += nudge; t.y += nudge; t.z += nudge; t.w += nudge;
        v[i] = t;
        red[r][q] = t.x * t.x + t.y * t.y + t.z * t.z + t.w * t.w;
    }
    __syncthreads();
    if (tid < RB) {
        float ss = 0.f;
        for (int j = 0; j < 32; j++) ss += red[tid][j];
        SInv[tid] = 1.0f / fmaxf(sqrtf(ss), EPSF);   // temporarily inv_norm
    }
    __syncthreads();
#pragma unroll
    for (int i = 0; i < 2; i++) {
        float inv = SInv[rA[i]];
        float4 t = v[i];
        t.x *= inv; t.y *= inv; t.z *= inv; t.w *= inv;
        reinterpret_cast<float4*>(&xs[rA[i]][0])[kq[i]] = t;
    }
    __syncthreads();

    // ---------------- GEMM1: logits = 2*(xn . cb^T) + noise ----------------
    const int rg = tid >> 5;       // 0..7 -> rows 2rg, 2rg+1
    const int cg = tid & 31;       // code within chunk
    const int r0 = rg * 2, r1 = r0 + 1;

    float bestv0 = -1e30f, bestv1 = -1e30f;
    int   besti0 = 0,      besti1 = 0;
    float m0 = -1e30f, m1 = -1e30f;

    for (int ch = 0; ch < NCH; ch++) {
        // stage 128k x 32c transposed tile
#pragma unroll
        for (int i = 0; i < 4; i++) {
            int g = tid + 256 * i;         // 0..1023 float4s
            int k = g >> 3, cq = g & 7;
            float4 t = reinterpret_cast<const float4*>(cbt_g)[k * (NC / 4) + ch * (C1 / 4) + cq];
            reinterpret_cast<float4*>(&cbuf[k * CBT_S])[cq] = t;
        }
        __syncthreads();

        float a0a = 0.f, a0b = 0.f, a1a = 0.f, a1b = 0.f;
#pragma unroll
        for (int k4 = 0; k4 < 32; k4++) {
            float4 a0 = reinterpret_cast<float4*>(&xs[r0][0])[k4];
            float4 a1 = reinterpret_cast<float4*>(&xs[r1][0])[k4];
            int kb = k4 * 4;
            float b0 = cbuf[(kb + 0) * CBT_S + cg];
            float b1 = cbuf[(kb + 1) * CBT_S + cg];
            float b2 = cbuf[(kb + 2) * CBT_S + cg];
            float b3 = cbuf[(kb + 3) * CBT_S + cg];
            a0a = fmaf(a0.x, b0, a0a); a0a = fmaf(a0.y, b1, a0a);
            a0b = fmaf(a0.z, b2, a0b); a0b = fmaf(a0.w, b3, a0b);
            a1a = fmaf(a1.x, b0, a1a); a1a = fmaf(a1.y, b1, a1a);
            a1b = fmaf(a1.z, b2, a1b); a1b = fmaf(a1.w, b3, a1b);
        }
        float acc0 = a0a + a0b;
        float acc1 = a1a + a1b;

        int c = ch * C1 + cg;
        if (acc0 > bestv0) { bestv0 = acc0; besti0 = c; }
        if (acc1 > bestv1) { bestv1 = acc1; besti1 = c; }
        float l0 = 2.f * acc0 + noise[(size_t)(row0 + r0) * NC + c];
        float l1 = 2.f * acc1 + noise[(size_t)(row0 + r1) * NC + c];
        m0 = fmaxf(m0, l0);
        m1 = fmaxf(m1, l1);
        logits[r0][c] = l0;
        logits[r1][c] = l1;
        __syncthreads();
    }

    // half-wave (32-lane) reductions: argmax(ab) with lowest-index ties, max(logit)
#pragma unroll
    for (int off = 16; off > 0; off >>= 1) {
        float ov = __shfl_xor(bestv0, off, 32);
        int   oi = __shfl_xor(besti0, off, 32);
        if (ov > bestv0 || (ov == bestv0 && oi < besti0)) { bestv0 = ov; besti0 = oi; }
        ov = __shfl_xor(bestv1, off, 32);
        oi = __shfl_xor(besti1, off, 32);
        if (ov > bestv1 || (ov == bestv1 && oi < besti1)) { bestv1 = ov; besti1 = oi; }
        m0 = fmaxf(m0, __shfl_xor(m0, off, 32));
        m1 = fmaxf(m1, __shfl_xor(m1, off, 32));
    }
    if (cg == 0) {
        Mrow[r0] = m0; Mrow[r1] = m1;
        out_i[row0 + r0] = (float)besti0;
        out_i[row0 + r1] = (float)besti1;
    }
    __syncthreads();

    // ---------------- softmax: exp in place, row sums ----------------
    {
        int r = tid >> 4, p = tid & 15;   // 16 threads/row, 32 codes each
        float M = Mrow[r];
        float lsum = 0.f;
        float4* lp = reinterpret_cast<float4*>(&logits[r][p * 32]);
#pragma unroll
        for (int j = 0; j < 8; j++) {
            float4 t = lp[j];
            t.x = __expf(t.x - M); t.y = __expf(t.y - M);
            t.z = __expf(t.z - M); t.w = __expf(t.w - M);
            lp[j] = t;
            lsum += (t.x + t.y) + (t.z + t.w);
        }
        red[r][p] = lsum;
    }
    __syncthreads();
    if (tid < RB) {
        float s = 0.f;
        for (int j = 0; j < 16; j++) s += red[tid][j];
        SInv[tid] = 1.0f / s;
    }
    __syncthreads();

    // ---------------- encodings write (coalesced float4) ----------------
    {
        const float4* lsrc = reinterpret_cast<const float4*>(&logits[0][0]);
        float4* eout = reinterpret_cast<float4*>(out_e + (size_t)row0 * NC);
#pragma unroll
        for (int i = 0; i < 8; i++) {
            int g = tid + 256 * i;        // 0..2047 float4s over 16x512
            float inv = SInv[g >> 7];
            float4 t = lsrc[g];
            t.x *= inv; t.y *= inv; t.z *= inv; t.w *= inv;
            eout[g] = t;
        }
    }

    // ---------------- GEMM2: quantized = (E . cb) * inv ----------------
    {
        const int dg = tid & 31;          // d0 = 4*dg
        float acc[2][4] = {{0.f, 0.f, 0.f, 0.f}, {0.f, 0.f, 0.f, 0.f}};
        float (*cbn)[CBN_S] = reinterpret_cast<float (*)[CBN_S]>(cbuf);
        for (int ch = 0; ch < 16; ch++) {
            __syncthreads();              // cbuf free from previous use
#pragma unroll
            for (int i = 0; i < 4; i++) {
                int g = tid + 256 * i;    // 0..1023 float4s over 32x128
                int c = g >> 5, dq = g & 31;
                float4 t = reinterpret_cast<const float4*>(cb)[(ch * 32 + c) * (DIM / 4) + dq];
                reinterpret_cast<float4*>(&cbn[c][0])[dq] = t;
            }
            __syncthreads();
#pragma unroll
            for (int cl = 0; cl < 32; cl++) {
                float e0 = logits[r0][ch * 32 + cl];
                float e1 = logits[r1][ch * 32 + cl];
                float4 b = reinterpret_cast<float4*>(&cbn[cl][0])[dg];
                acc[0][0] = fmaf(e0, b.x, acc[0][0]);
                acc[0][1] = fmaf(e0, b.y, acc[0][1]);
                acc[0][2] = fmaf(e0, b.z, acc[0][2]);
                acc[0][3] = fmaf(e0, b.w, acc[0][3]);
                acc[1][0] = fmaf(e1, b.x, acc[1][0]);
                acc[1][1] = fmaf(e1, b.y, acc[1][1]);
                acc[1][2] = fmaf(e1, b.z, acc[1][2]);
                acc[1][3] = fmaf(e1, b.w, acc[1][3]);
            }
        }
        float inv0 = SInv[r0], inv1 = SInv[r1];
        float4 q0 = {acc[0][0] * inv0, acc[0][1] * inv0, acc[0][2] * inv0, acc[0][3] * inv0};
        float4 q1 = {acc[1][0] * inv1, acc[1][1] * inv1, acc[1][2] * inv1, acc[1][3] * inv1};
        reinterpret_cast<float4*>(out_q + (size_t)(row0 + r0) * DIM)[dg] = q0;
        reinterpret_cast<float4*>(out_q + (size_t)(row0 + r1) * DIM)[dg] = q1;
    }
}

extern "C" void kernel_launch(void* const* d_in, const int* in_sizes, int n_in,
                              void* d_out, int out_size, void* d_ws, size_t ws_size,
                              hipStream_t stream)
{
    const float* x     = (const float*)d_in[0];
    const float* mask  = (const float*)d_in[1];
    const float* cb    = (const float*)d_in[2];
    const float* noise = (const float*)d_in[3];

    float* out_q = (float*)d_out;                       // n*128
    float* out_e = out_q + (size_t)N_TOK * DIM;         // n*512
    float* out_i = out_e + (size_t)N_TOK * NC;          // n (indices as float)

    float* cbt = (float*)d_ws;                          // 512*128 floats = 256 KB scratch

    hipLaunchKernelGGL(transpose_cb, dim3(256), dim3(256), 0, stream, cb, cbt);
    hipLaunchKernelGGL(vq_main, dim3(NBLK), dim3(256), 0, stream,
                       x, mask, cb, cbt, noise, out_q, out_e, out_i);
}